// Round 1
// baseline (1576.847 us; speedup 1.0000x reference)
//
#include <hip/hip_runtime.h>

#define T_STEPS 512
#define D_IN    32
#define H       64
#define NG      256   // 4*H gate rows per layer
#define NB      4     // batch elements per block

__device__ __forceinline__ float sigf(float x) {
    return 1.0f / (1.0f + __expf(-x));
}
__device__ __forceinline__ float tanhf_(float x) {
    // stable: e->inf gives 1, e->0 gives -1 (no inf/inf)
    float e = __expf(2.0f * x);
    return 1.0f - 2.0f / (e + 1.0f);
}

// dot of K4*4 elements: register weights vs LDS float4 (wave-uniform broadcast reads)
template<int K4>
__device__ __forceinline__ float dot4(const float* w, const float4* p) {
    float acc = 0.0f;
#pragma unroll
    for (int q = 0; q < K4; ++q) {
        float4 v = p[q];
        acc += w[4*q+0] * v.x;
        acc += w[4*q+1] * v.y;
        acc += w[4*q+2] * v.z;
        acc += w[4*q+3] * v.w;
    }
    return acc;
}

__global__ __launch_bounds__(512, 2)
void lstm2_fused(const float* __restrict__ x,
                 const float* __restrict__ Wih0, const float* __restrict__ Whh0,
                 const float* __restrict__ bih0, const float* __restrict__ bhh0,
                 const float* __restrict__ Wih1, const float* __restrict__ Whh1,
                 const float* __restrict__ bih1, const float* __restrict__ bhh1,
                 const float* __restrict__ Wfc,  const float* __restrict__ bfc,
                 float* __restrict__ out)
{
    __shared__ __align__(16) float xbuf[2][NB][D_IN];
    __shared__ __align__(16) float h0buf[2][NB][H];
    __shared__ __align__(16) float h1buf[2][NB][H];
    __shared__ __align__(16) float gbuf[2][NB][NG];

    const int tid   = threadIdx.x;
    const int layer = tid >> 8;     // 0: waves 0-3, 1: waves 4-7 (wave-uniform)
    const int j     = tid & 255;    // gate row within layer
    const int b0    = blockIdx.x * NB;

    // ---- per-thread register weights ----
    float wa[H];   // layer0: W_ih0 row (32 used); layer1: W_ih1 row (64)
    float wb[H];   // W_hh row (64)
    float bias;
    if (layer == 0) {
        const float* pa = Wih0 + j * D_IN;
#pragma unroll
        for (int k = 0; k < D_IN; ++k) wa[k] = pa[k];
        const float* pb = Whh0 + j * H;
#pragma unroll
        for (int k = 0; k < H; ++k) wb[k] = pb[k];
        bias = bih0[j] + bhh0[j];
    } else {
        const float* pa = Wih1 + j * H;
#pragma unroll
        for (int k = 0; k < H; ++k) wa[k] = pa[k];
        const float* pb = Whh1 + j * H;
#pragma unroll
        for (int k = 0; k < H; ++k) wb[k] = pb[k];
        bias = bih1[j] + bhh1[j];
    }

    // state element handled by this thread in phase C
    const int b_s = (tid & 255) >> 6;  // 0..3
    const int j_s = tid & 63;          // 0..63
    float c_state = 0.0f;

    // ---- init: zero "previous" h buffers, stage x_0 ----
    if (tid < NB * H) {
        int b = tid >> 6, k = tid & 63;
        h0buf[1][b][k] = 0.0f;   // read by layer0 at it=0 (pprev=1)
        h1buf[0][b][k] = 0.0f;   // read by layer1 at it=1 (pprev=0)
    }
    if (tid < NB * D_IN) {
        int b = tid >> 5, k = tid & 31;
        xbuf[0][b][k] = x[(size_t)(b0 + b) * T_STEPS * D_IN + k];
    }
    __syncthreads();

    for (int it = 0; it <= T_STEPS; ++it) {
        const int pcur  = it & 1;
        const int pprev = pcur ^ 1;

        // register-prefetch x_{it+1} (latency hidden behind gate compute)
        float xpre = 0.0f;
        const bool have_x = (tid < NB * D_IN) && (it + 1 < T_STEPS);
        if (have_x) {
            int b = tid >> 5, k = tid & 31;
            xpre = x[(size_t)(b0 + b) * T_STEPS * D_IN + (size_t)(it + 1) * D_IN + k];
        }

        // ---- phase A: gate matvecs (layer0 at step it, layer1 at step it-1) ----
        if (layer == 0) {
            if (it < T_STEPS) {
#pragma unroll
                for (int b = 0; b < NB; ++b) {
                    float acc = bias;
                    acc += dot4<D_IN/4>(wa, (const float4*)&xbuf[pcur][b][0]);
                    acc += dot4<H/4>(wb, (const float4*)&h0buf[pprev][b][0]);
                    gbuf[0][b][j] = acc;
                }
            }
        } else {
            if (it >= 1) {
#pragma unroll
                for (int b = 0; b < NB; ++b) {
                    float acc = bias;
                    acc += dot4<H/4>(wa, (const float4*)&h0buf[pprev][b][0]);
                    acc += dot4<H/4>(wb, (const float4*)&h1buf[pprev][b][0]);
                    gbuf[1][b][j] = acc;
                }
            }
        }
        __syncthreads();

        // ---- phase C: elementwise LSTM cell update ----
        const bool active = (layer == 0) ? (it < T_STEPS) : (it >= 1);
        if (active) {
            float ig = gbuf[layer][b_s][0 * H + j_s];
            float fg = gbuf[layer][b_s][1 * H + j_s];
            float gg = gbuf[layer][b_s][2 * H + j_s];
            float og = gbuf[layer][b_s][3 * H + j_s];
            float cc = sigf(fg) * c_state + sigf(ig) * tanhf_(gg);
            c_state = cc;
            float hh = sigf(og) * tanhf_(cc);
            if (layer == 0) h0buf[pcur][b_s][j_s] = hh;
            else            h1buf[pcur][b_s][j_s] = hh;
        }
        if (have_x) {
            int b = tid >> 5, k = tid & 31;
            xbuf[pprev][b][k] = xpre;   // (it+1)&1 == pprev
        }
        __syncthreads();
    }

    // ---- final FC: out[b] = h1_last . Wfc + bfc ----
    if (tid < NB) {
        const int pl = T_STEPS & 1;   // layer1's last write parity (it = T_STEPS)
        float s = bfc[0];
#pragma unroll
        for (int k = 0; k < H; ++k) s += h1buf[pl][tid][k] * Wfc[k];
        out[b0 + tid] = s;
    }
}

extern "C" void kernel_launch(void* const* d_in, const int* in_sizes, int n_in,
                              void* d_out, int out_size, void* d_ws, size_t ws_size,
                              hipStream_t stream) {
    const float* x    = (const float*)d_in[0];
    const float* Wih0 = (const float*)d_in[1];
    const float* Whh0 = (const float*)d_in[2];
    const float* bih0 = (const float*)d_in[3];
    const float* bhh0 = (const float*)d_in[4];
    const float* Wih1 = (const float*)d_in[5];
    const float* Whh1 = (const float*)d_in[6];
    const float* bih1 = (const float*)d_in[7];
    const float* bhh1 = (const float*)d_in[8];
    const float* Wfc  = (const float*)d_in[9];
    const float* bfc  = (const float*)d_in[10];
    float* out = (float*)d_out;

    const int B = out_size;            // 1024
    dim3 grid(B / NB), block(512);
    hipLaunchKernelGGL(lstm2_fused, grid, block, 0, stream,
                       x, Wih0, Whh0, bih0, bhh0,
                       Wih1, Whh1, bih1, bhh1, Wfc, bfc, out);
}

// Round 2
// 1308.043 us; speedup vs baseline: 1.2055x; 1.2055x over previous
//
#include <hip/hip_runtime.h>

#define T_STEPS 512
#define D_IN    32
#define H       64
#define NB      4     // batch elements per block

// ---- DPP cross-lane add helpers (VALU pipe, no LDS) ----
template<int CTRL>
__device__ __forceinline__ float dpp_add(float v) {
    int m = __builtin_amdgcn_update_dpp(0, __float_as_int(v), CTRL, 0xf, 0xf, true);
    return v + __int_as_float(m);
}
// full sum over the 8 lanes sharing (lane>>3); result in all 8 lanes
__device__ __forceinline__ float red8(float v) {
    v = dpp_add<0xB1>(v);   // quad_perm [1,0,3,2]  : + lane^1
    v = dpp_add<0x4E>(v);   // quad_perm [2,3,0,1]  : + lane^2
    v = dpp_add<0x141>(v);  // row_half_mirror      : + other quad (7-i)
    return v;
}

__device__ __forceinline__ float sigf(float x) {
    return 1.0f / (1.0f + __expf(-x));
}
__device__ __forceinline__ float tanhf_(float x) {
    float e = __expf(2.0f * x);
    return 1.0f - 2.0f / (e + 1.0f);
}

// quad-swizzled float index for the L1 input vector u1[b][128] = {h0(64), h1(64)}
// chunk c = k>>4 (16 floats), quad q = (k>>2)&3, elem e = k&3
__device__ __forceinline__ int swz1(int k) {
    int c = k >> 4, q = (k >> 2) & 3, e = k & 3;
    return 16 * c + ((q ^ (c & 3)) << 2) + e;
}

__global__ __launch_bounds__(1024, 4)
void lstm2_fused(const float* __restrict__ x,
                 const float* __restrict__ Wih0, const float* __restrict__ Whh0,
                 const float* __restrict__ bih0, const float* __restrict__ bhh0,
                 const float* __restrict__ Wih1, const float* __restrict__ Whh1,
                 const float* __restrict__ bih1, const float* __restrict__ bhh1,
                 const float* __restrict__ Wfc,  const float* __restrict__ bfc,
                 float* __restrict__ out)
{
    // L0 input: vin[b] = { x_t (32) , h0 (64) }  (contiguous; chunk reads are
    // bank-quad (3c+q)%8 -> all distinct -> conflict-free)
    __shared__ __align__(16) float vin[NB][96];
    // L1 input: u1[b] = { h0 (64), h1 (64) } quad-XOR-swizzled (2-way only = free)
    __shared__ __align__(16) float u1[NB][128];
    __shared__ float g0buf[NB][256];
    __shared__ float g1buf[NB][256];

    const int tid  = threadIdx.x;
    const int b0   = blockIdx.x * NB;
    const int lane = tid & 63;
    const int c    = lane & 7;        // K-chunk
    const int g    = lane >> 3;       // row-slot within pass
    const bool isL0 = tid < 512;
    const int  w    = (tid >> 6) & 7; // wave index within layer group (0..7)

    // ---- per-thread weights: L0 48 floats (12-float chunk x 4 rows),
    //                          L1 64 floats (16-float chunk x 4 rows) ----
    float wreg[64];
    if (isL0) {
#pragma unroll
        for (int p = 0; p < 4; ++p) {
            int r = w * 32 + p * 8 + g;
#pragma unroll
            for (int kk = 0; kk < 12; ++kk) {
                int k = 12 * c + kk;
                wreg[p * 12 + kk] = (k < 32) ? Wih0[r * D_IN + k]
                                             : Whh0[r * H + (k - 32)];
            }
        }
    } else {
#pragma unroll
        for (int p = 0; p < 4; ++p) {
            int r = w * 32 + p * 8 + g;
#pragma unroll
            for (int kk = 0; kk < 16; ++kk) {
                int k = 16 * c + kk;
                wreg[p * 16 + kk] = (k < 64) ? Wih1[r * H + k]
                                             : Whh1[r * H + (k - 64)];
            }
        }
    }

    // ---- phase-C state owners ----
    // h0 states: threads [0,256)    (b = tid>>6, j = tid&63)
    // h1 states: threads [512,768)
    // x staging: threads [768,896)
    const int jst = tid & 63;
    const int bst = (tid >> 6) & 3;
    float bi = 0.f, bff = 0.f, bg = 0.f, bo = 0.f, cst = 0.f;
    if (tid < 256) {
        bi  = bih0[jst]       + bhh0[jst];
        bff = bih0[64 + jst]  + bhh0[64 + jst];
        bg  = bih0[128 + jst] + bhh0[128 + jst];
        bo  = bih0[192 + jst] + bhh0[192 + jst];
    } else if (tid >= 512 && tid < 768) {
        bi  = bih1[jst]       + bhh1[jst];
        bff = bih1[64 + jst]  + bhh1[64 + jst];
        bg  = bih1[128 + jst] + bhh1[128 + jst];
        bo  = bih1[192 + jst] + bhh1[192 + jst];
    }

    // ---- init: zero h-state LDS, stage x_0 ----
    if (tid < 512) ((float*)u1)[tid] = 0.f;                       // NB*128 = 512
    if (tid >= 512 && tid < 768) vin[(tid - 512) >> 6][32 + ((tid - 512) & 63)] = 0.f;
    if (tid >= 768 && tid < 896) {
        int t2 = tid - 768, b = t2 >> 5, k = t2 & 31;
        vin[b][k] = x[(size_t)(b0 + b) * T_STEPS * D_IN + k];
    }
    __syncthreads();

    for (int it = 0; it <= T_STEPS; ++it) {
        // register-prefetch x_{it+1}
        float xpre = 0.f;
        const bool havex = (tid >= 768 && tid < 896) && (it + 1 < T_STEPS);
        if (havex) {
            int t2 = tid - 768, b = t2 >> 5, k = t2 & 31;
            xpre = x[(size_t)(b0 + b) * T_STEPS * D_IN + (size_t)(it + 1) * D_IN + k];
        }

        // ---- phase A: chunked gate matvecs ----
        if (isL0) {
            if (it < T_STEPS) {
#pragma unroll
                for (int b = 0; b < NB; ++b) {
                    const float4* v4 = (const float4*)&vin[b][0];
                    float4 A = v4[3 * c], B4 = v4[3 * c + 1], C4 = v4[3 * c + 2];
                    float in_s[12] = {A.x, A.y, A.z, A.w, B4.x, B4.y, B4.z, B4.w,
                                      C4.x, C4.y, C4.z, C4.w};
#pragma unroll
                    for (int p = 0; p < 4; ++p) {
                        float acc = 0.f;
#pragma unroll
                        for (int kk = 0; kk < 12; ++kk) acc += wreg[p * 12 + kk] * in_s[kk];
                        acc = red8(acc);
                        if (c == 0) g0buf[b][w * 32 + p * 8 + g] = acc;
                    }
                }
            }
        } else {
            if (it >= 1) {
#pragma unroll
                for (int b = 0; b < NB; ++b) {
                    const float4* v4 = (const float4*)&u1[b][0];
                    // chunk c occupies quad slots 4c..4c+3, quad q at 4c + (q^(c&3))
                    float4 qv0 = v4[4 * c + ((0 ^ (c & 3)))];
                    float4 qv1 = v4[4 * c + ((1 ^ (c & 3)))];
                    float4 qv2 = v4[4 * c + ((2 ^ (c & 3)))];
                    float4 qv3 = v4[4 * c + ((3 ^ (c & 3)))];
                    float in_s[16] = {qv0.x, qv0.y, qv0.z, qv0.w,
                                      qv1.x, qv1.y, qv1.z, qv1.w,
                                      qv2.x, qv2.y, qv2.z, qv2.w,
                                      qv3.x, qv3.y, qv3.z, qv3.w};
#pragma unroll
                    for (int p = 0; p < 4; ++p) {
                        float acc = 0.f;
#pragma unroll
                        for (int kk = 0; kk < 16; ++kk) acc += wreg[p * 16 + kk] * in_s[kk];
                        acc = red8(acc);
                        if (c == 0) g1buf[b][w * 32 + p * 8 + g] = acc;
                    }
                }
            }
        }
        __syncthreads();

        // ---- phase C: cell updates + x commit ----
        if (tid < 256) {
            if (it < T_STEPS) {
                float gi = g0buf[bst][jst]       + bi;
                float gf = g0buf[bst][64 + jst]  + bff;
                float gg = g0buf[bst][128 + jst] + bg;
                float go = g0buf[bst][192 + jst] + bo;
                float cc = sigf(gf) * cst + sigf(gi) * tanhf_(gg);
                cst = cc;
                float hh = sigf(go) * tanhf_(cc);
                vin[bst][32 + jst] = hh;          // L0's next-step input
                u1[bst][swz1(jst)] = hh;          // L1's input (swizzled)
            }
        } else if (tid >= 512 && tid < 768) {
            if (it >= 1) {
                float gi = g1buf[bst][jst]       + bi;
                float gf = g1buf[bst][64 + jst]  + bff;
                float gg = g1buf[bst][128 + jst] + bg;
                float go = g1buf[bst][192 + jst] + bo;
                float cc = sigf(gf) * cst + sigf(gi) * tanhf_(gg);
                cst = cc;
                u1[bst][swz1(64 + jst)] = sigf(go) * tanhf_(cc);
            }
        }
        if (havex) {
            int t2 = tid - 768, b = t2 >> 5, k = t2 & 31;
            vin[b][k] = xpre;
        }
        __syncthreads();
    }

    // ---- final FC on h1[T-1] ----
    if (tid < NB) {
        float s = bfc[0];
#pragma unroll
        for (int k = 0; k < H; ++k) s += u1[tid][swz1(64 + k)] * Wfc[k];
        out[b0 + tid] = s;
    }
}

extern "C" void kernel_launch(void* const* d_in, const int* in_sizes, int n_in,
                              void* d_out, int out_size, void* d_ws, size_t ws_size,
                              hipStream_t stream) {
    const float* x    = (const float*)d_in[0];
    const float* Wih0 = (const float*)d_in[1];
    const float* Whh0 = (const float*)d_in[2];
    const float* bih0 = (const float*)d_in[3];
    const float* bhh0 = (const float*)d_in[4];
    const float* Wih1 = (const float*)d_in[5];
    const float* Whh1 = (const float*)d_in[6];
    const float* bih1 = (const float*)d_in[7];
    const float* bhh1 = (const float*)d_in[8];
    const float* Wfc  = (const float*)d_in[9];
    const float* bfc  = (const float*)d_in[10];
    float* out = (float*)d_out;

    const int B = out_size;            // 1024
    dim3 grid(B / NB), block(1024);
    hipLaunchKernelGGL(lstm2_fused, grid, block, 0, stream,
                       x, Wih0, Whh0, bih0, bhh0,
                       Wih1, Whh1, bih1, bhh1, Wfc, bfc, out);
}